// Round 9
// baseline (161.562 us; speedup 1.0000x reference)
//
#include <hip/hip_runtime.h>

// Lorenz96 RK4, fp32 — fat threads (8 elems/chunk) + persistent depth-2:
//   Surviving theory after 7 invariant structures (~50us, no pipe >43%):
//   VALU (~20us) and memory (~20-27us) ALTERNATE instead of overlapping.
//   r6's depth-1 ping-pong hides only ~300cy of ~900cy load latency
//   (compute phase too short) -> VALU duty ~33%, matching measured 40%.
//   Fix: 8-element chunks. Window [p-8,p+11] = 5 aligned float4s of the
//   row (cols 2cp-2..2cp+2 mod 10). Per chunk: 5 loads + 2 stores per 8
//   outputs (VMEM-inst/elem -30%, read-amp 4x->2.5x), ~28 VALU/elem
//   (vs 37), and a ~2x longer compute phase so depth-2 prefetch covers
//   the latency. nf8 = 2,621,440 = 5 x 524,288 exactly: persistent
//   2048x256 grid, 5 chunks/thread, fully unrolled, branchless, named
//   slots only (no runtime-indexed arrays -> no scratch).
//   (Round-8 submission hit "container failed twice" — same infra flake
//   signature as round 5, which passed cleanly on identical-source
//   resubmission. Kernel re-audited: coverage exact, no OOB, no barriers,
//   no hang vectors. Resubmitting unchanged.)

#define FORCE 8.0f

typedef float f32x4 __attribute__((ext_vector_type(4)));

__device__ __forceinline__ void nt_store(float4* p, const float4& v) {
    __builtin_nontemporal_store(*(const f32x4*)&v, (f32x4*)p);
}

struct f4x2 { float4 a, b; };

// RK4 on an 8-element output span from a 20-element window (5 float4s).
// Window pos p+i maps: k1[i]~pos i+2 (i<17), k2[i]~pos i+4 (i<14),
// k3[i]~pos i+6 (i<11), k4[i]~pos i+8 (i<8); outputs pos 8..15.
__device__ __forceinline__ f4x2 rk4_chunk8(const float4 w0, const float4 w1,
                                           const float4 w2, const float4 w3,
                                           const float4 w4,
                                           const float dt, const float hdt)
{
    float xa[20];
    xa[0]=w0.x;  xa[1]=w0.y;  xa[2]=w0.z;  xa[3]=w0.w;
    xa[4]=w1.x;  xa[5]=w1.y;  xa[6]=w1.z;  xa[7]=w1.w;
    xa[8]=w2.x;  xa[9]=w2.y;  xa[10]=w2.z; xa[11]=w2.w;
    xa[12]=w3.x; xa[13]=w3.y; xa[14]=w3.z; xa[15]=w3.w;
    xa[16]=w4.x; xa[17]=w4.y; xa[18]=w4.z; xa[19]=w4.w;

    float k1[17], y1[17];
#pragma unroll
    for (int i = 0; i < 17; ++i)
        k1[i] = fmaf(xa[i+3] - xa[i], xa[i+1], FORCE - xa[i+2]);
#pragma unroll
    for (int i = 0; i < 17; ++i)
        y1[i] = fmaf(hdt, k1[i], xa[i+2]);

    float k2[14], y2[14];
#pragma unroll
    for (int i = 0; i < 14; ++i)
        k2[i] = fmaf(y1[i+3] - y1[i], y1[i+1], FORCE - y1[i+2]);
#pragma unroll
    for (int i = 0; i < 14; ++i)
        y2[i] = fmaf(hdt, k2[i], xa[i+4]);

    float k3[11], y3[11];
#pragma unroll
    for (int i = 0; i < 11; ++i)
        k3[i] = fmaf(y2[i+3] - y2[i], y2[i+1], FORCE - y2[i+2]);
#pragma unroll
    for (int i = 0; i < 11; ++i)
        y3[i] = fmaf(dt, k3[i], xa[i+6]);

    float k4[8];
#pragma unroll
    for (int i = 0; i < 8; ++i)
        k4[i] = fmaf(y3[i+3] - y3[i], y3[i+1], FORCE - y3[i+2]);

    const float sc = dt * (1.0f / 6.0f);
    float o[8];
#pragma unroll
    for (int m = 0; m < 8; ++m) {
        float t = k1[m+6] + k4[m];
        t = fmaf(2.0f, k2[m+4], t);
        t = fmaf(2.0f, k3[m+2], t);
        o[m] = fmaf(sc, t, xa[8+m]);
    }
    f4x2 r;
    r.a = make_float4(o[0], o[1], o[2], o[3]);
    r.b = make_float4(o[4], o[5], o[6], o[7]);
    return r;
}

// 5 window loads for chunk g (f8 index), cp = g mod 5.
// rowbase rb = 2*(g-cp) [f4]; own pair at rb+2cp, rb+2cp+1 (== 2g, 2g+1).
#define LOADS8(G, CP, W0, W1, W2, W3, W4)                                    \
    {                                                                        \
        const unsigned rb  = 2u * ((G) - (CP));                              \
        const unsigned two = 2u * (CP);                                      \
        const unsigned cm2 = ((CP) == 0u) ? 8u : two - 2u;                   \
        const unsigned cm1 = ((CP) == 0u) ? 9u : two - 1u;                   \
        const unsigned cp2 = ((CP) == 4u) ? 0u : two + 2u;                   \
        W0 = x0[rb + cm2];                                                   \
        W1 = x0[rb + cm1];                                                   \
        W2 = x0[rb + two];                                                   \
        W3 = x0[rb + two + 1u];                                              \
        W4 = x0[rb + cp2];                                                   \
    }

#define STORE8(G, R)                                                         \
    {                                                                        \
        nt_store(&out[2u * (G)],      R.a);                                  \
        nt_store(&out[2u * (G) + 1u], R.b);                                  \
    }

// ---------- fat path: exactly 5 chunks/thread (nf8 == 5 * stride) ----------
__global__ __launch_bounds__(256)
void lorenz96_rk4_fat8(const float4* __restrict__ x0,
                       const float* __restrict__ dt_p,
                       float4* __restrict__ out,
                       unsigned stride)    // total threads; stride % 5 == 3
{
    const unsigned tid = blockIdx.x * blockDim.x + threadIdx.x;
    const float dt  = dt_p[0];
    const float hdt = 0.5f * dt;

    // chunk indices g_i = tid + i*stride, cp_i = g_i mod 5 (cpstep = 3)
    unsigned g0 = tid;
    unsigned c0 = tid % 5u;
    unsigned g1 = g0 + stride;
    unsigned c1 = c0 + 3u; if (c1 >= 5u) c1 -= 5u;

    float4 A0, A1, A2, A3, A4;     // slot A
    float4 B0, B1, B2, B3, B4;     // slot B
    LOADS8(g0, c0, A0, A1, A2, A3, A4)          // chunk 0 -> A
    LOADS8(g1, c1, B0, B1, B2, B3, B4)          // chunk 1 -> B

    // chunk 0: compute A, refill A <- chunk 2
    f4x2 r0 = rk4_chunk8(A0, A1, A2, A3, A4, dt, hdt);
    STORE8(g0, r0)
    {
        const unsigned g2 = g1 + stride;
        unsigned c2 = c1 + 3u; if (c2 >= 5u) c2 -= 5u;
        LOADS8(g2, c2, A0, A1, A2, A3, A4)
        g0 = g2; c0 = c2;
    }

    // chunk 1: compute B, refill B <- chunk 3
    f4x2 r1 = rk4_chunk8(B0, B1, B2, B3, B4, dt, hdt);
    STORE8(g1, r1)
    {
        const unsigned g3 = g0 + stride;
        unsigned c3 = c0 + 3u; if (c3 >= 5u) c3 -= 5u;
        LOADS8(g3, c3, B0, B1, B2, B3, B4)
        g1 = g3; c1 = c3;
    }

    // chunk 2: compute A, refill A <- chunk 4
    f4x2 r2 = rk4_chunk8(A0, A1, A2, A3, A4, dt, hdt);
    STORE8(g0, r2)
    {
        const unsigned g4 = g1 + stride;
        unsigned c4 = c1 + 3u; if (c4 >= 5u) c4 -= 5u;
        LOADS8(g4, c4, A0, A1, A2, A3, A4)
        g0 = g4; c0 = c4;
    }

    // chunk 3: compute B
    f4x2 r3 = rk4_chunk8(B0, B1, B2, B3, B4, dt, hdt);
    STORE8(g1, r3)

    // chunk 4: compute A
    f4x2 r4 = rk4_chunk8(A0, A1, A2, A3, A4, dt, hdt);
    STORE8(g0, r4)
}

// ---------- fallback: generic one-shot halo kernel (any size) --------------
__device__ __forceinline__ float4 rk4_chunk4(const float4 vm2, const float4 vm1,
                                             const float4 v0,  const float4 vp1,
                                             const float dt,   const float hdt)
{
    float xa[16];
    xa[0]=vm2.x;  xa[1]=vm2.y;  xa[2]=vm2.z;  xa[3]=vm2.w;
    xa[4]=vm1.x;  xa[5]=vm1.y;  xa[6]=vm1.z;  xa[7]=vm1.w;
    xa[8]=v0.x;   xa[9]=v0.y;   xa[10]=v0.z;  xa[11]=v0.w;
    xa[12]=vp1.x; xa[13]=vp1.y; xa[14]=vp1.z; xa[15]=vp1.w;

    float k1[13], y1[13];
#pragma unroll
    for (int i = 0; i < 13; ++i)
        k1[i] = fmaf(xa[i+3] - xa[i], xa[i+1], FORCE - xa[i+2]);
#pragma unroll
    for (int i = 0; i < 13; ++i)
        y1[i] = fmaf(hdt, k1[i], xa[i+2]);

    float k2[10], y2[10];
#pragma unroll
    for (int i = 0; i < 10; ++i)
        k2[i] = fmaf(y1[i+3] - y1[i], y1[i+1], FORCE - y1[i+2]);
#pragma unroll
    for (int i = 0; i < 10; ++i)
        y2[i] = fmaf(hdt, k2[i], xa[i+4]);

    float k3[7], y3[7];
#pragma unroll
    for (int i = 0; i < 7; ++i)
        k3[i] = fmaf(y2[i+3] - y2[i], y2[i+1], FORCE - y2[i+2]);
#pragma unroll
    for (int i = 0; i < 7; ++i)
        y3[i] = fmaf(dt, k3[i], xa[i+6]);

    float k4[4];
#pragma unroll
    for (int i = 0; i < 4; ++i)
        k4[i] = fmaf(y3[i+3] - y3[i], y3[i+1], FORCE - y3[i+2]);

    const float sc = dt * (1.0f / 6.0f);
    float4 r;
    float t0 = k1[6] + k4[0]; t0 = fmaf(2.0f, k2[4], t0); t0 = fmaf(2.0f, k3[2], t0);
    float t1 = k1[7] + k4[1]; t1 = fmaf(2.0f, k2[5], t1); t1 = fmaf(2.0f, k3[3], t1);
    float t2 = k1[8] + k4[2]; t2 = fmaf(2.0f, k2[6], t2); t2 = fmaf(2.0f, k3[4], t2);
    float t3 = k1[9] + k4[3]; t3 = fmaf(2.0f, k2[7], t3); t3 = fmaf(2.0f, k3[5], t3);
    r.x = fmaf(sc, t0, xa[8]);
    r.y = fmaf(sc, t1, xa[9]);
    r.z = fmaf(sc, t2, xa[10]);
    r.w = fmaf(sc, t3, xa[11]);
    return r;
}

__global__ __launch_bounds__(256)
void lorenz96_rk4_halo(const float4* __restrict__ x0,
                       const float* __restrict__ dt_p,
                       float4* __restrict__ out,
                       long nf4)
{
    const long f = (long)blockIdx.x * blockDim.x + threadIdx.x;
    if (f >= nf4) return;
    const long r  = f / 10;
    const int  c  = (int)(f - r * 10);
    const long rb = r * 10;
    const int cm2 = (c >= 2) ? c - 2 : c + 8;
    const int cm1 = (c >= 1) ? c - 1 : c + 9;
    const int cp1 = (c <= 8) ? c + 1 : c - 9;

    const float4 vm2 = x0[rb + cm2];
    const float4 vm1 = x0[rb + cm1];
    const float4 v0  = x0[rb + c  ];
    const float4 vp1 = x0[rb + cp1];

    const float dt  = dt_p[0];
    const float hdt = 0.5f * dt;
    const float4 res = rk4_chunk4(vm2, vm1, v0, vp1, dt, hdt);
    nt_store(&out[f], res);
}

extern "C" void kernel_launch(void* const* d_in, const int* in_sizes, int n_in,
                              void* d_out, int out_size, void* d_ws, size_t ws_size,
                              hipStream_t stream) {
    const float4* x0 = (const float4*)d_in[0];
    // d_in[1] = t (unused; autonomous system)
    const float* dt = (const float*)d_in[2];
    float4* out = (float4*)d_out;

    const long nf4 = (long)in_sizes[0] / 4;        // batch*10 float4s
    const int block = 256;
    const unsigned grid = 2048;                    // persistent, 8 blocks/CU
    const unsigned stride = grid * (unsigned)block;  // 524288 threads

    const long nf8 = nf4 / 2;
    if (nf4 % 2 == 0 && (unsigned long)nf8 == 5ul * stride) {
        lorenz96_rk4_fat8<<<dim3(grid), dim3(block), 0, stream>>>(
            x0, dt, out, stride);
    } else {
        const long g = (nf4 + block - 1) / block;
        lorenz96_rk4_halo<<<dim3((unsigned)g), dim3(block), 0, stream>>>(
            x0, dt, out, nf4);
    }
}